// Round 3
// baseline (199.687 us; speedup 1.0000x reference)
//
#include <hip/hip_runtime.h>
#include <hip/hip_fp16.h>

#define N     4096
#define SIZE  128
#define CAP   128   // row stride in ints (unchanged from round-1 footprint)
#define NMAX  120   // max stored neighbors; NMAX+8 sentinels fit in CAP stride
#define RB    8     // output rows per block -> 64KB LDS, 2 blocks/CU
#define TB    1024  // threads per block (fused kernel)

typedef __attribute__((ext_vector_type(8))) _Float16 f16x8;  // MFMA A/B frag (4 VGPRs)
typedef __attribute__((ext_vector_type(2))) __fp16 fp16x2;   // cvt_pkrtz return type
typedef __attribute__((ext_vector_type(4))) float f32x4;     // MFMA C/D frag

__device__ __forceinline__ unsigned int pk2(float lo, float hi) {
    union { fp16x2 v; unsigned int u; } c;
    c.v = __builtin_amdgcn_cvt_pkrtz(lo, hi);   // 1 instr, RTZ
    return c.u;
}
__device__ __forceinline__ __half2 u2h(unsigned int u) {
    union { unsigned int u; __half2 h; } c; c.u = u; return c.h;
}

// ---- setup: blocks [0,N) build padded CSR rows; blocks [N,N+256) prep MFMA frags ----
// CSR: per-thread 16-bit nz mask + wave shfl-scan. Self-edge (diag) is DROPPED here;
// fused adds it back in the epilogue (numerator read == self term).
__global__ __launch_bounds__(256)
void setup(const float* __restrict__ nb, const float* __restrict__ f,
           const float* __restrict__ wq, const float* __restrict__ wk,
           int* __restrict__ cnt, int* __restrict__ idx,
           _Float16* __restrict__ Af, _Float16* __restrict__ Bf) {
    __shared__ int   wtot[4];
    __shared__ float sf[SIZE][16];
    __shared__ float sqw[SIZE];
    const int t = threadIdx.x;

    if (blockIdx.x < N) {
        // ---------------- CSR build ----------------
        const int j    = blockIdx.x;
        const int lane = t & 63;
        const int wv   = t >> 6;
        const float4* row4 = (const float4*)(nb + (size_t)j * N);
        int* irow = idx + (size_t)j * CAP;

        float4 v[4];
#pragma unroll
        for (int it = 0; it < 4; ++it) v[it] = row4[t + it * 256];

        unsigned int msk = 0u;            // bit (it*4+q) = nz of col 4*(t+it*256)+q
#pragma unroll
        for (int it = 0; it < 4; ++it) {
            const float e[4] = {v[it].x, v[it].y, v[it].z, v[it].w};
#pragma unroll
            for (int q = 0; q < 4; ++q)
                if (e[q] != 0.0f) msk |= 1u << (it * 4 + q);
        }
        // drop self edge: col j owned by thread (j>>2)&255, segment j>>10, quad j&3
        if (((j >> 2) & 255) == t) msk &= ~(1u << ((j >> 10) * 4 + (j & 3)));

        const int pc = __popc(msk);
        int scan = pc;                    // wave inclusive prefix sum (6 shfl steps)
#pragma unroll
        for (int s = 1; s < 64; s <<= 1) {
            const int o = __shfl_up(scan, s);
            if (lane >= s) scan += o;
        }
        if (lane == 63) wtot[wv] = scan;
        __syncthreads();
        int base = 0;
#pragma unroll
        for (int w = 0; w < 3; ++w)
            if (w < wv) base += wtot[w];
        int p = base + scan - pc;         // exclusive offset
        unsigned int m = msk;
        while (m) {
            const int b = __ffs(m) - 1;
            m &= m - 1u;
            const int c = 4 * (t + (b >> 2) * 256) + (b & 3);
            if (p < NMAX) irow[p] = c;
            ++p;
        }
        if (t == 255) {                   // wv=3,lane=63: base+scan = row total
            int n = base + scan;
            if (n > NMAX) n = NMAX;
            const int n8 = (n + 7) & ~7;  // <= 120
            // sentinels through n8+8 (<= 128) so next-chunk prefetch is branch-free
            for (int q = n; q < n8 + 8; ++q) irow[q] = N;
            cnt[j] = n8 >> 3;             // 8-neighbor chunks (may be 0)
        }
    } else {
        // ---------------- fragment prep (mapping unchanged, verified) ----------------
        const int tile = blockIdx.x - N;
        if (t < SIZE) sqw[t] = wq[t] * wk[t];
        const int col0 = t & 15;
#pragma unroll
        for (int it = 0; it < 8; ++it) {
            const int k = (t >> 4) + it * 16;
            sf[k][col0] = f[(size_t)k * N + tile * 16 + col0];
        }
        __syncthreads();
        const int ks   = t >> 6;
        const int lane = t & 63;
        const int quad = lane >> 4;
        const int col  = lane & 15;
        f16x8 va, vb;
#pragma unroll
        for (int jj = 0; jj < 8; ++jj) {
            const int k = ks * 32 + quad * 8 + jj;
            const float v = sf[k][col];
            va[jj] = (_Float16)(sqw[k] * v);
            vb[jj] = (_Float16)v;
        }
        const size_t o = (size_t)(tile * 4 + ks) * 64 + lane;
        ((f16x8*)Af)[o] = va;
        ((f16x8*)Bf)[o] = vb;
    }
}

// ---- fused: 8 output rows per block, 64KB S-tile -> 2 blocks/CU (8 waves/SIMD) ----
__global__ __launch_bounds__(TB, 8)
void fused(const _Float16* __restrict__ Af, const _Float16* __restrict__ Bf,
           const int* __restrict__ cnt, const int* __restrict__ idx,
           float* __restrict__ out) {
    __shared__ uint4 sA[N + 2];               // 65,568 B; sA[N] = zero sentinel
    const int t    = threadIdx.x;
    const int lane = t & 63;
    const int wv   = t >> 6;
    const int quad = lane >> 4;
    const int bid  = blockIdx.x;
    const int i0   = bid * RB;

    if (t == 0) sA[N] = make_uint4(0u, 0u, 0u, 0u);

    // prefetch u=0 gather metadata BEFORE phase 1 + barrier (hides L2 latency)
    int cc = cnt[t];
    const int4* ir0 = (const int4*)(idx + (size_t)t * CAP);
    int4 ka = ir0[0];
    int4 kb = ir0[1];

    // ---- phase 1: S rows i0..i0+7 for all 4096 columns ----
    f16x8 af[4];
    const f16x8* Ap = (const f16x8*)Af + (size_t)(bid >> 1) * 4 * 64;
#pragma unroll
    for (int ks = 0; ks < 4; ++ks) af[ks] = Ap[ks * 64 + lane];
    const f16x8* Bp = (const f16x8*)Bf;
    // C/D: col = lane&15, row = quad*4+reg; even block keeps rows 0-7 (quads 0,1),
    // odd block rows 8-15 (quads 2,3)
    const bool sel = (quad >> 1) == (bid & 1);

#pragma unroll 4
    for (int ti = 0; ti < 16; ++ti) {
        const int nt = wv * 16 + ti;          // column tile: j = nt*16 .. nt*16+15
        f32x4 acc = {0.f, 0.f, 0.f, 0.f};
#pragma unroll
        for (int ks = 0; ks < 4; ++ks) {
            const f16x8 bfrag = Bp[(size_t)(nt * 4 + ks) * 64 + lane];
            acc = __builtin_amdgcn_mfma_f32_16x16x32_f16(af[ks], bfrag, acc, 0, 0, 0);
        }
        if (sel) {
            const int j = nt * 16 + (lane & 15);
            uint2 pp;
            pp.x = pk2(__expf(acc[0]), __expf(acc[1]));
            pp.y = pk2(__expf(acc[2]), __expf(acc[3]));
            ((uint2*)&sA[j])[quad & 1] = pp;  // local rows (quad&1)*4 .. +3
        }
    }
    __syncthreads();

#define ACC4(D, A) \
    D[0] = __hadd2(D[0], u2h((A).x)); D[1] = __hadd2(D[1], u2h((A).y)); \
    D[2] = __hadd2(D[2], u2h((A).z)); D[3] = __hadd2(D[3], u2h((A).w));

    // ---- phase 2: sparse gather, 8 neighbors/iter, branch-free prefetch ----
    for (int u = 0; u < 4; ++u) {
        const int j = t + u * TB;
        const int4* ir = (const int4*)(idx + (size_t)j * CAP);
        // rolling prefetch of next u's metadata (hidden under this u's gather)
        int ncc = 0; int4 nk0 = ka, nk1 = kb;
        if (u < 3) {
            const int jn = j + TB;
            const int4* irn = (const int4*)(idx + (size_t)jn * CAP);
            ncc = cnt[jn];
            nk0 = irn[0];
            nk1 = irn[1];
        }
        __half2 d0[4], d1[4], d2[4], d3[4];   // 4 independent chains
        const __half2 z = u2h(0u);
#pragma unroll
        for (int r = 0; r < 4; ++r) { d0[r] = z; d1[r] = z; d2[r] = z; d3[r] = z; }

        for (int c = 0; c < cc; ++c) {
            const int4 pa = ir[2 * c + 2];    // sentinel-padded: always in-bounds
            const int4 pb = ir[2 * c + 3];
            const uint4 ax = sA[ka.x], ay = sA[ka.y];
            const uint4 az = sA[ka.z], aw = sA[ka.w];
            const uint4 ex = sA[kb.x], ey = sA[kb.y];
            const uint4 ez = sA[kb.z], ew = sA[kb.w];
            ACC4(d0, ax) ACC4(d1, ay) ACC4(d0, az) ACC4(d1, aw)
            ACC4(d2, ex) ACC4(d3, ey) ACC4(d2, ez) ACC4(d3, ew)
            ka = pa; kb = pb;
        }
        const uint4 nn4 = sA[j];              // numerators == self term of denominator
        const unsigned int nu[4] = {nn4.x, nn4.y, nn4.z, nn4.w};
#pragma unroll
        for (int i = 0; i < 4; ++i) {
            const __half2 nn = u2h(nu[i]);
            __half2 dd = __hadd2(__hadd2(d0[i], d1[i]), __hadd2(d2[i], d3[i]));
            dd = __hadd2(dd, nn);             // add self edge back
            __builtin_nontemporal_store(
                __low2float(nn)  * __builtin_amdgcn_rcpf(__low2float(dd)),
                &out[(size_t)(i0 + 2 * i + 0) * N + j]);
            __builtin_nontemporal_store(
                __high2float(nn) * __builtin_amdgcn_rcpf(__high2float(dd)),
                &out[(size_t)(i0 + 2 * i + 1) * N + j]);
        }
        cc = ncc; ka = nk0; kb = nk1;
    }
#undef ACC4
}

extern "C" void kernel_launch(void* const* d_in, const int* in_sizes, int n_in,
                              void* d_out, int out_size, void* d_ws, size_t ws_size,
                              hipStream_t stream) {
    const float* f  = (const float*)d_in[0];   // [SIZE, N]
    const float* nb = (const float*)d_in[1];   // [N, N]
    const float* wq = (const float*)d_in[2];   // [SIZE]
    const float* wk = (const float*)d_in[3];   // [SIZE]
    float* out = (float*)d_out;                // [N, N]

    // workspace: cnt (N int) | idx (N*CAP int) | Af (512K f16) | Bf (512K f16) ~= 4.0 MB
    int*      cnt = (int*)d_ws;
    int*      idx = cnt + N;
    _Float16* Af  = (_Float16*)(idx + (size_t)N * CAP);
    _Float16* Bf  = Af + (size_t)256 * 4 * 64 * 8;

    setup<<<N + 256, 256, 0, stream>>>(nb, f, wq, wk, cnt, idx, Af, Bf);
    fused<<<N / RB, TB, 0, stream>>>(Af, Bf, cnt, idx, out);
}

// Round 4
// 147.803 us; speedup vs baseline: 1.3510x; 1.3510x over previous
//
#include <hip/hip_runtime.h>
#include <hip/hip_fp16.h>

#define N     4096
#define SIZE  128
#define CAP   128   // row stride in ints
#define NMAX  120   // max stored neighbors; NMAX+8 sentinels fit in CAP stride
#define RB    16    // output rows per block (one 16-row MFMA M-tile) -> 128KB LDS
#define TB    1024  // threads per block (fused kernel)

typedef __attribute__((ext_vector_type(8))) _Float16 f16x8;  // MFMA A/B frag (4 VGPRs)
typedef __attribute__((ext_vector_type(2))) __fp16 fp16x2;   // cvt_pkrtz return type
typedef __attribute__((ext_vector_type(4))) float f32x4;     // MFMA C/D frag

__device__ __forceinline__ unsigned int pk2(float lo, float hi) {
    union { fp16x2 v; unsigned int u; } c;
    c.v = __builtin_amdgcn_cvt_pkrtz(lo, hi);   // 1 instr, RTZ
    return c.u;
}
__device__ __forceinline__ __half2 u2h(unsigned int u) {
    union { unsigned int u; __half2 h; } c; c.u = u; return c.h;
}

// ---- setup: blocks [0,1024) build CSR (one WAVE per row, 4 rows/block);
//      blocks [1024,1024+256) prep MFMA fragments.
// CSR: 16 float4 loads/lane in flight, 64-bit nz mask, wave-local shfl scan.
// No LDS, no __syncthreads -> pure streaming of the 64MB adjacency.
// Self-edge (diag) DROPPED; fused adds it back in the epilogue.
__global__ __launch_bounds__(256)
void setup(const float* __restrict__ nb, const float* __restrict__ f,
           const float* __restrict__ wq, const float* __restrict__ wk,
           int* __restrict__ cnt, int* __restrict__ idx,
           _Float16* __restrict__ Af, _Float16* __restrict__ Bf) {
    __shared__ float sf[SIZE][16];
    __shared__ float sqw[SIZE];
    const int t = threadIdx.x;

    if (blockIdx.x < N / 4) {
        // ---------------- CSR build: wave wv owns row j ----------------
        const int lane = t & 63;
        const int wv   = t >> 6;
        const int j    = blockIdx.x * 4 + wv;
        const float4* row4 = (const float4*)(nb + (size_t)j * N);
        int* irow = idx + (size_t)j * CAP;

        float4 v[16];
#pragma unroll
        for (int s = 0; s < 16; ++s) v[s] = row4[s * 64 + lane];  // coalesced

        unsigned long long m = 0ull;      // bit (s*4+q) = nz of col 4*(s*64+lane)+q
#pragma unroll
        for (int s = 0; s < 16; ++s) {
            const float e[4] = {v[s].x, v[s].y, v[s].z, v[s].w};
#pragma unroll
            for (int q = 0; q < 4; ++q)
                if (e[q] != 0.0f) m |= 1ull << (s * 4 + q);
        }
        // drop self edge: col j -> lane (j>>2)&63, bit (j>>8)*4 + (j&3)
        if (((j >> 2) & 63) == lane) m &= ~(1ull << ((j >> 8) * 4 + (j & 3)));

        const int pc = __popcll(m);
        int scan = pc;                    // wave inclusive prefix sum (6 shfl steps)
#pragma unroll
        for (int s = 1; s < 64; s <<= 1) {
            const int o = __shfl_up(scan, s);
            if (lane >= s) scan += o;
        }
        int p = scan - pc;                // exclusive offset within row
        unsigned long long mm = m;
        while (mm) {
            const int b = __ffsll(mm) - 1;
            mm &= mm - 1ull;
            const int c = 4 * ((b >> 2) * 64 + lane) + (b & 3);
            if (p < NMAX) irow[p] = c;
            ++p;
        }
        if (lane == 63) {                 // scan == row total here
            int n = scan;
            if (n > NMAX) n = NMAX;
            const int n8 = (n + 7) & ~7;  // <= 120
            // sentinels through n8+8 (<=128) so next-chunk prefetch is branch-free
            for (int q = n; q < n8 + 8; ++q) irow[q] = N;
            cnt[j] = n8 >> 3;             // 8-neighbor chunks (may be 0)
        }
    } else {
        // ---------------- fragment prep (mapping unchanged, verified) ----------------
        const int tile = blockIdx.x - N / 4;
        if (t < SIZE) sqw[t] = wq[t] * wk[t];
        const int col0 = t & 15;
#pragma unroll
        for (int it = 0; it < 8; ++it) {
            const int k = (t >> 4) + it * 16;
            sf[k][col0] = f[(size_t)k * N + tile * 16 + col0];
        }
        __syncthreads();
        const int ks   = t >> 6;
        const int lane = t & 63;
        const int quad = lane >> 4;
        const int col  = lane & 15;
        f16x8 va, vb;
#pragma unroll
        for (int jj = 0; jj < 8; ++jj) {
            const int k = ks * 32 + quad * 8 + jj;
            const float v = sf[k][col];
            va[jj] = (_Float16)(sqw[k] * v);
            vb[jj] = (_Float16)v;
        }
        const size_t o = (size_t)(tile * 4 + ks) * 64 + lane;
        ((f16x8*)Af)[o] = va;
        ((f16x8*)Bf)[o] = vb;
    }
}

// ---- fused: 16 output rows per block (round-1 structure: ILP > occupancy) ----
__global__ __launch_bounds__(TB, 4)
void fused(const _Float16* __restrict__ Af, const _Float16* __restrict__ Bf,
           const int* __restrict__ cnt, const int* __restrict__ idx,
           float* __restrict__ out) {
    // sA: rows 0-7 (8 f16/column), sB: rows 8-15; sB offset +2 slots; +1 slot each
    // is the zeroed sentinel (index N).
    __shared__ uint4 Sb[2 * N + 3];           // 131,120 B -> 1 block/CU
    uint4* const sA = Sb;
    uint4* const sB = Sb + N + 2;
    const int t    = threadIdx.x;
    const int lane = t & 63;
    const int wv   = t >> 6;
    const int quad = lane >> 4;
    const int i0   = blockIdx.x * RB;

    if (t == 0) {
        sA[N] = make_uint4(0u, 0u, 0u, 0u);
        sB[N] = make_uint4(0u, 0u, 0u, 0u);
    }

    // prefetch u=0 gather metadata BEFORE phase 1 + barrier (hides L2 latency)
    int cc = cnt[t];
    const int4* ir0 = (const int4*)(idx + (size_t)t * CAP);
    int4 ka = ir0[0];
    int4 kb = ir0[1];

    // ---- phase 1 ----
    f16x8 af[4];
    const f16x8* Ap = (const f16x8*)Af + (size_t)blockIdx.x * 4 * 64;
#pragma unroll
    for (int ks = 0; ks < 4; ++ks) af[ks] = Ap[ks * 64 + lane];
    const f16x8* Bp = (const f16x8*)Bf;

#pragma unroll 4
    for (int ti = 0; ti < 16; ++ti) {
        const int nt = wv * 16 + ti;          // column tile: j = nt*16 .. nt*16+15
        f32x4 acc = {0.f, 0.f, 0.f, 0.f};
#pragma unroll
        for (int ks = 0; ks < 4; ++ks) {
            const f16x8 bfrag = Bp[(size_t)(nt * 4 + ks) * 64 + lane];
            acc = __builtin_amdgcn_mfma_f32_16x16x32_f16(af[ks], bfrag, acc, 0, 0, 0);
        }
        // C/D: col = lane&15, row = quad*4 + reg
        const int j = nt * 16 + (lane & 15);
        uint2 pp;
        pp.x = pk2(__expf(acc[0]), __expf(acc[1]));
        pp.y = pk2(__expf(acc[2]), __expf(acc[3]));
        uint2* bs = (quad < 2) ? (uint2*)&sA[j] : (uint2*)&sB[j];
        bs[quad & 1] = pp;
    }
    __syncthreads();

#define ACC(D, A, B) \
    D[0] = __hadd2(D[0], u2h((A).x)); D[1] = __hadd2(D[1], u2h((A).y)); \
    D[2] = __hadd2(D[2], u2h((A).z)); D[3] = __hadd2(D[3], u2h((A).w)); \
    D[4] = __hadd2(D[4], u2h((B).x)); D[5] = __hadd2(D[5], u2h((B).y)); \
    D[6] = __hadd2(D[6], u2h((B).z)); D[7] = __hadd2(D[7], u2h((B).w));

    // ---- phase 2: sparse gather, 8 neighbors/iter, branch-free prefetch ----
    for (int u = 0; u < 4; ++u) {
        const int j = t + u * TB;
        const int4* ir = (const int4*)(idx + (size_t)j * CAP);
        // rolling prefetch of next u's metadata (hidden under this u's gather)
        int ncc = 0; int4 nk0 = ka, nk1 = kb;
        if (u < 3) {
            const int jn = j + TB;
            const int4* irn = (const int4*)(idx + (size_t)jn * CAP);
            ncc = cnt[jn];
            nk0 = irn[0];
            nk1 = irn[1];
        }
        __half2 d0[8], d1[8], d2[8], d3[8];   // 4 independent chains
        const __half2 z = u2h(0u);
#pragma unroll
        for (int r = 0; r < 8; ++r) { d0[r] = z; d1[r] = z; d2[r] = z; d3[r] = z; }

        for (int c = 0; c < cc; ++c) {
            const int4 pa = ir[2 * c + 2];    // sentinel-padded: always in-bounds
            const int4 pb = ir[2 * c + 3];
            const uint4 ax = sA[ka.x], bx = sB[ka.x];
            const uint4 ay = sA[ka.y], by = sB[ka.y];
            const uint4 az = sA[ka.z], bz = sB[ka.z];
            const uint4 aw = sA[ka.w], bw = sB[ka.w];
            const uint4 ex = sA[kb.x], fx = sB[kb.x];
            const uint4 ey = sA[kb.y], fy = sB[kb.y];
            const uint4 ez = sA[kb.z], fz = sB[kb.z];
            const uint4 ew = sA[kb.w], fw = sB[kb.w];
            ACC(d0, ax, bx)
            ACC(d1, ay, by)
            ACC(d0, az, bz)
            ACC(d1, aw, bw)
            ACC(d2, ex, fx)
            ACC(d3, ey, fy)
            ACC(d2, ez, fz)
            ACC(d3, ew, fw)
            ka = pa; kb = pb;
        }
        const uint4 na4 = sA[j], nb4 = sB[j];  // numerators == self term of denom
        const unsigned int nu[8] = {na4.x, na4.y, na4.z, na4.w,
                                    nb4.x, nb4.y, nb4.z, nb4.w};
#pragma unroll
        for (int i = 0; i < 8; ++i) {
            const __half2 nn = u2h(nu[i]);
            __half2 dd = __hadd2(__hadd2(d0[i], d1[i]), __hadd2(d2[i], d3[i]));
            dd = __hadd2(dd, nn);             // add self edge back
            out[(size_t)(i0 + 2 * i + 0) * N + j] =
                __low2float(nn)  * __builtin_amdgcn_rcpf(__low2float(dd));
            out[(size_t)(i0 + 2 * i + 1) * N + j] =
                __high2float(nn) * __builtin_amdgcn_rcpf(__high2float(dd));
        }
        cc = ncc; ka = nk0; kb = nk1;
    }
#undef ACC
}

extern "C" void kernel_launch(void* const* d_in, const int* in_sizes, int n_in,
                              void* d_out, int out_size, void* d_ws, size_t ws_size,
                              hipStream_t stream) {
    const float* f  = (const float*)d_in[0];   // [SIZE, N]
    const float* nb = (const float*)d_in[1];   // [N, N]
    const float* wq = (const float*)d_in[2];   // [SIZE]
    const float* wk = (const float*)d_in[3];   // [SIZE]
    float* out = (float*)d_out;                // [N, N]

    // workspace: cnt (N int) | idx (N*CAP int) | Af (512K f16) | Bf (512K f16) ~= 4.0 MB
    int*      cnt = (int*)d_ws;
    int*      idx = cnt + N;
    _Float16* Af  = (_Float16*)(idx + (size_t)N * CAP);
    _Float16* Bf  = Af + (size_t)256 * 4 * 64 * 8;

    setup<<<N / 4 + 256, 256, 0, stream>>>(nb, f, wq, wk, cnt, idx, Af, Bf);
    fused<<<N / RB, TB, 0, stream>>>(Af, Bf, cnt, idx, out);
}